// Round 10
// baseline (306.628 us; speedup 1.0000x reference)
//
#include <hip/hip_runtime.h>
#include <hip/hip_bf16.h>

// GraphSAGE inference, MI355X. R10: group-sum LDS epilogue -> no C1 materialization.
//  L1: gather_self(Hall) | weights cast | zero(out) | zero(M1f) | mean10 rows<12800
//  L2: gemm0-SELF  -> M1f cols 0-511 (group-sum) / C0 cols 0-511   | mean10 rest | H0m
//  L3: gemm0-NEIGH -> M1f cols 512+ (group-sum) / C0 cols 512+
//  L4: m1cvt (M1 = bf16(M1f/25)) | gemm1-pass0 (C0@Ws1, atomics on out)
//  L5: gemm1-pass1 (M1@Wn1, atomics on out)

#define DEVINL __device__ __forceinline__

typedef __bf16 bf16x8 __attribute__((ext_vector_type(8)));
typedef float f32x4 __attribute__((ext_vector_type(4)));

DEVINL unsigned short f2bf(float f) {
  union { float f; unsigned u; } v; v.f = f;
  unsigned r = v.u + 0x7FFFu + ((v.u >> 16) & 1u);  // RNE
  return (unsigned short)(r >> 16);
}
DEVINL float bf2f(unsigned short h) {
  union { unsigned u; float f; } v; v.u = ((unsigned)h) << 16;
  return v.f;
}

DEVINL void gload_lds16(const void* g, void* l) {
  __builtin_amdgcn_global_load_lds(
      (const __attribute__((address_space(1))) void*)g,
      (__attribute__((address_space(3))) void*)l, 16, 0, 0);
}

// ---- NT GEMM core: 128x128 tile, BK in {32,64}, 4 waves 2x2, 16x16x32 bf16 MFMA.
// EPI 0 (layer0): tm<25600 -> LDS group-sum of relu'd rows -> M1f (direct store for
//                 full 25-row groups, 1 global atomic for the <=2 boundary groups);
//                 tm>=25600 -> bf16 store to C0[row-25600][col0+...].
// EPI 1 (layer1): f32 atomicAdd into out (split-K).
template <int EPI, int BK>
DEVINL void gemm_core(const unsigned short* __restrict__ A, int lda,
                      const unsigned short* __restrict__ Bt, int ldb,
                      int Kc, long tm, long tn, int col0,
                      unsigned short* __restrict__ C0, float* __restrict__ M1f,
                      float* __restrict__ out, int ldc,
                      unsigned short* As, unsigned short* Bs) {
  const int t = threadIdx.x;
  const int w = t >> 6;
  const int l = t & 63;
  const int wm = w >> 1, wn = w & 1;
  f32x4 acc[4][4] = {};
  constexpr int LPR = BK / 8;            // lanes per row (16B chunks)
  constexpr int RPW = 64 / LPR;          // rows per wave-gload
  constexpr int ROUNDS = 128 / (4 * RPW);
  constexpr int NS = BK / 32;            // k-slices per iter
  const int s_r = l / LPR;
  const int s_kc = (l % LPR) * 8;

  for (int kt = 0; kt < Kc; kt += BK) {
    __syncthreads();  // LDS free
    #pragma unroll
    for (int r = 0; r < ROUNDS; ++r) {
      const int chunk = r * (4 * RPW) + w * RPW;
      gload_lds16(A + (size_t)(tm + chunk + s_r) * lda + kt + s_kc, As + chunk * BK);
      gload_lds16(Bt + (size_t)(tn + chunk + s_r) * ldb + kt + s_kc, Bs + chunk * BK);
    }
    __syncthreads();  // staged (barrier drains vmcnt)

    bf16x8 af[4][NS], bfr[4][NS];
    const unsigned short* Ab = As + ((size_t)(wm * 64 + (l & 15)) * BK + (l >> 4) * 8);
    const unsigned short* Bb = Bs + ((size_t)(wn * 64 + (l & 15)) * BK + (l >> 4) * 8);
    #pragma unroll
    for (int f = 0; f < 4; ++f)
      #pragma unroll
      for (int s = 0; s < NS; ++s) {
        af[f][s] = *reinterpret_cast<const bf16x8*>(Ab + f * 16 * BK + s * 32);
        bfr[f][s] = *reinterpret_cast<const bf16x8*>(Bb + f * 16 * BK + s * 32);
      }
    #pragma unroll
    for (int s = 0; s < NS; ++s)   // K ascending (matches prior rounds' numerics)
      #pragma unroll
      for (int i = 0; i < 4; ++i)
        #pragma unroll
        for (int j = 0; j < 4; ++j)
          acc[i][j] = __builtin_amdgcn_mfma_f32_16x16x32_bf16(af[i][s], bfr[j][s], acc[i][j], 0, 0, 0);
  }

  // epilogue: C/D layout col = l&15, row = (l>>4)*4 + r  [m89/m91 verified]
  const int q = l >> 4, cl = l & 15;
  if (EPI == 0) {
    if (tm < 25600) {  // tiles never straddle 25600 (25600 % 128 == 0)
      __syncthreads();                       // all waves done reading As
      float* gsum = (float*)As;              // 7*128 floats = 3.5 KB
      for (int z = t; z < 7 * 128; z += 256) gsum[z] = 0.f;
      __syncthreads();
      const int g0 = (int)tm / 25;
      #pragma unroll
      for (int i = 0; i < 4; ++i)
        #pragma unroll
        for (int j = 0; j < 4; ++j)
          #pragma unroll
          for (int r = 0; r < 4; ++r) {
            const float v = fmaxf(acc[i][j][r], 0.f);
            const int grow = (int)tm + wm * 64 + i * 16 + q * 4 + r;
            const int gl = grow / 25 - g0;   // 0..6
            atomicAdd(&gsum[gl * 128 + wn * 64 + j * 16 + cl], v);
          }
      __syncthreads();
      for (int z = t; z < 7 * 128; z += 256) {
        const int gl = z >> 7, cloc = z & 127;
        const int g = g0 + gl;
        const int gs = g * 25, ge = gs + 25;
        if (gs >= (int)tm + 128) continue;   // slot beyond tile
        float* dst = M1f + (size_t)g * 1024 + col0 + tn + cloc;
        if (gs >= (int)tm && ge <= (int)tm + 128) *dst = gsum[z];   // full group: exclusive
        else atomicAdd(dst, gsum[z]);                               // boundary: 2-way
      }
    } else {
      #pragma unroll
      for (int i = 0; i < 4; ++i)
        #pragma unroll
        for (int j = 0; j < 4; ++j)
          #pragma unroll
          for (int r = 0; r < 4; ++r) {
            const long row = tm - 25600 + wm * 64 + i * 16 + q * 4 + r;
            const long col = col0 + tn + wn * 64 + j * 16 + cl;
            C0[row * 1024 + col] = f2bf(fmaxf(acc[i][j][r], 0.f));
          }
    }
  } else {
    #pragma unroll
    for (int i = 0; i < 4; ++i)
      #pragma unroll
      for (int j = 0; j < 4; ++j)
        #pragma unroll
        for (int r = 0; r < 4; ++r) {
          const long row = tm + wm * 64 + i * 16 + q * 4 + r;
          const long col = tn + wn * 64 + j * 16 + cl;
          atomicAdd(out + row * ldc + col, acc[i][j][r]);
        }
  }
}

// ---- mean10 of x rows -> bf16 Hmall row (2 rows/block, 256 thr)
DEVINL void mean10_row(const float* __restrict__ x, const int* __restrict__ neigh2,
                       unsigned short* __restrict__ Hmall, int row, int tid) {
  int c4 = (tid & 127) << 2;
  float4 acc = {0.f, 0.f, 0.f, 0.f};
  const int* ip = neigh2 + (size_t)row * 10;
  #pragma unroll
  for (int j = 0; j < 10; ++j) {
    const float4 v = *reinterpret_cast<const float4*>(x + (size_t)ip[j] * 512 + c4);
    acc.x += v.x; acc.y += v.y; acc.z += v.z; acc.w += v.w;
  }
  const float s = 0.1f;
  ushort4 o; o.x = f2bf(acc.x * s); o.y = f2bf(acc.y * s);
  o.z = f2bf(acc.z * s); o.w = f2bf(acc.w * s);
  *reinterpret_cast<ushort4*>(Hmall + (size_t)row * 512 + c4) = o;
}

// ---- L1: gather_self (13312) | weights (4096) | zero out (256) | zero M1f (1024) | mean10 lo (6400)
__global__ __launch_bounds__(256) void phaseA_kernel(
    const float* __restrict__ x, const int* __restrict__ neigh1, const int* __restrict__ nodes,
    const int* __restrict__ neigh2,
    const float* __restrict__ Ws0, const float* __restrict__ Wn0,
    const float* __restrict__ Ws1, const float* __restrict__ Wn1,
    unsigned short* __restrict__ Hall, unsigned short* __restrict__ Hmall,
    unsigned short* __restrict__ WT0s, unsigned short* __restrict__ WT0n,
    unsigned short* __restrict__ WT1s, unsigned short* __restrict__ WT1n,
    float* __restrict__ M1f, float* __restrict__ out) {
  const int b = blockIdx.x;
  const int tid = threadIdx.x;
  if (b < 13312) {  // gather_self: 2 rows/block
    int row = b * 2 + (tid >> 7);
    int src = row < 25600 ? neigh1[row] : nodes[row - 25600];
    int c4 = (tid & 127) << 2;
    const float4 v = *reinterpret_cast<const float4*>(x + (size_t)src * 512 + c4);
    ushort4 o; o.x = f2bf(v.x); o.y = f2bf(v.y); o.z = f2bf(v.z); o.w = f2bf(v.w);
    *reinterpret_cast<ushort4*>(Hall + (size_t)row * 512 + c4) = o;
  } else if (b < 13312 + 4096) {  // weights -> bf16 [N][K]
    int t = (b - 13312) * 256 + tid;
    int region = t >> 18, local = t & 262143;
    const float* W; unsigned short* WT;
    if (region == 0)      { W = Ws0; WT = WT0s; }
    else if (region == 1) { W = Wn0; WT = WT0n; }
    else if (region == 2) { W = Ws1; WT = WT1s; }
    else                  { W = Wn1; WT = WT1n; }
    int k, n, N;
    if (region < 2) { k = local & 511;  n = local >> 9;  N = 512; }
    else            { k = local & 1023; n = local >> 10; N = 256; }
    WT[local] = f2bf(W[(size_t)k * N + n]);
  } else if (b < 17664) {  // zero out (1 MB)
    int t = (b - 17408) * 256 + tid;
    reinterpret_cast<float4*>(out)[t] = float4{0.f, 0.f, 0.f, 0.f};
  } else if (b < 18688) {  // zero M1f (4 MB)
    int t = (b - 17664) * 256 + tid;
    reinterpret_cast<float4*>(M1f)[t] = float4{0.f, 0.f, 0.f, 0.f};
  } else {  // mean10 rows 0-12799
    mean10_row(x, neigh2, Hmall, (b - 18688) * 2 + (tid >> 7), tid);
  }
}

// ---- L2: gemm0-self (832) | mean10 rows>=12800 (6400) | mean25(Hall)->H0m (512)
__global__ __launch_bounds__(256) void phaseB_kernel(
    const float* __restrict__ x, const int* __restrict__ neigh2,
    const unsigned short* __restrict__ Hall, const unsigned short* __restrict__ WT0s,
    unsigned short* __restrict__ Hmall,
    unsigned short* __restrict__ C0, float* __restrict__ M1f) {
  __shared__ __align__(16) unsigned short As[128 * 32];
  __shared__ __align__(16) unsigned short Bs[128 * 32];
  const int b = blockIdx.x;
  const int tid = threadIdx.x;
  if (b < 832) {  // self half: cols 0-511, all 26624 rows
    const long tm = (long)(b >> 2) * 128;
    const long tn = (long)(b & 3) * 128;
    gemm_core<0, 32>(Hall, 512, WT0s, 512, 512, tm, tn, 0, C0, M1f, nullptr, 0, As, Bs);
  } else if (b < 832 + 6400) {  // mean10 rows 12800-25599
    mean10_row(x, neigh2, Hmall, 12800 + (b - 832) * 2 + (tid >> 7), tid);
  } else {  // H0m = mean25 of Hall bf16 rows -> Hmall rows 25600+
    int g = (b - 7232) * 2 + (tid >> 7);
    int c4 = (tid & 127) << 2;
    float a0 = 0, a1 = 0, a2 = 0, a3 = 0;
    for (int j = 0; j < 25; ++j) {
      ushort4 v = *reinterpret_cast<const ushort4*>(Hall + ((size_t)g * 25 + j) * 512 + c4);
      a0 += bf2f(v.x); a1 += bf2f(v.y); a2 += bf2f(v.z); a3 += bf2f(v.w);
    }
    const float s = 1.0f / 25.0f;
    ushort4 o; o.x = f2bf(a0 * s); o.y = f2bf(a1 * s); o.z = f2bf(a2 * s); o.w = f2bf(a3 * s);
    *reinterpret_cast<ushort4*>(Hmall + ((size_t)25600 + g) * 512 + c4) = o;
  }
}

// ---- L3: gemm0-neighbor (832): cols 512-1023
__global__ __launch_bounds__(256) void phaseC_kernel(
    const unsigned short* __restrict__ Hmall, const unsigned short* __restrict__ WT0n,
    unsigned short* __restrict__ C0, float* __restrict__ M1f) {
  __shared__ __align__(16) unsigned short As[128 * 32];
  __shared__ __align__(16) unsigned short Bs[128 * 32];
  const long tm = (long)(blockIdx.x >> 2) * 128;
  const long tn = (long)(blockIdx.x & 3) * 128;
  gemm_core<0, 32>(Hmall, 512, WT0n, 512, 512, tm, tn, 512, C0, M1f, nullptr, 0, As, Bs);
}

// ---- L4: m1cvt (1024) | gemm1-pass0 (64)
__global__ __launch_bounds__(256) void phaseD_kernel(
    const float* __restrict__ M1f, unsigned short* __restrict__ M1,
    const unsigned short* __restrict__ C0, const unsigned short* __restrict__ WT1s,
    float* __restrict__ out) {
  __shared__ __align__(16) unsigned short As[128 * 64];
  __shared__ __align__(16) unsigned short Bs[128 * 64];
  const int b = blockIdx.x;
  if (b < 1024) {  // M1 = bf16(M1f / 25)
    int t = b * 256 + threadIdx.x;
    const float4 v = reinterpret_cast<const float4*>(M1f)[t];
    const float s = 1.0f / 25.0f;
    ushort4 o; o.x = f2bf(v.x * s); o.y = f2bf(v.y * s); o.z = f2bf(v.z * s); o.w = f2bf(v.w * s);
    reinterpret_cast<ushort4*>(M1)[t] = o;
  } else {  // out += C0@Ws1, split-K4
    const int u = b - 1024;
    const int z = u >> 4, bm = (u >> 1) & 7, bn = u & 1;
    gemm_core<1, 64>(C0 + z * 256, 1024, WT1s + z * 256, 1024, 256,
                     (long)bm * 128, (long)bn * 128, 0, nullptr, nullptr, out, 256, As, Bs);
  }
}

// ---- L5: gemm1-pass1 (64): out += M1@Wn1, split-K4
__global__ __launch_bounds__(256) void phaseE_kernel(
    const unsigned short* __restrict__ M1, const unsigned short* __restrict__ WT1n,
    float* __restrict__ out) {
  __shared__ __align__(16) unsigned short As[128 * 64];
  __shared__ __align__(16) unsigned short Bs[128 * 64];
  const int b = blockIdx.x;
  const int z = b >> 4, bm = (b >> 1) & 7, bn = b & 1;
  gemm_core<1, 64>(M1 + z * 256, 1024, WT1n + z * 256, 1024, 256,
                   (long)bm * 128, (long)bn * 128, 0, nullptr, nullptr, out, 256, As, Bs);
}

extern "C" void kernel_launch(void* const* d_in, const int* in_sizes, int n_in,
                              void* d_out, int out_size, void* d_ws, size_t ws_size,
                              hipStream_t stream) {
  const float* x      = (const float*)d_in[0];   // [200000, 512]
  const int*   nodes  = (const int*)d_in[1];     // [1024]
  const int*   neigh1 = (const int*)d_in[2];     // [25600]
  const int*   neigh2 = (const int*)d_in[3];     // [256000]
  const float* Ws0    = (const float*)d_in[4];   // [512, 512]
  const float* Wn0    = (const float*)d_in[5];   // [512, 512]
  const float* Ws1    = (const float*)d_in[6];   // [1024, 256]
  const float* Wn1    = (const float*)d_in[7];   // [1024, 256]
  float* out = (float*)d_out;                    // [1024, 256]

  char* p = (char*)d_ws;
  unsigned short* WT0s  = (unsigned short*)p; p += (size_t)512 * 512 * 2;
  unsigned short* WT0n  = (unsigned short*)p; p += (size_t)512 * 512 * 2;
  unsigned short* WT1s  = (unsigned short*)p; p += (size_t)256 * 1024 * 2;
  unsigned short* WT1n  = (unsigned short*)p; p += (size_t)256 * 1024 * 2;
  unsigned short* Hall  = (unsigned short*)p; p += (size_t)26624 * 512 * 2;
  unsigned short* Hmall = (unsigned short*)p; p += (size_t)26624 * 512 * 2;
  unsigned short* C0    = (unsigned short*)p; p += (size_t)1024 * 1024 * 2;
  unsigned short* M1    = (unsigned short*)p; p += (size_t)1024 * 1024 * 2;
  float*          M1f   = (float*)p;          p += (size_t)1024 * 1024 * 4;

  hipLaunchKernelGGL(phaseA_kernel, dim3(25088), dim3(256), 0, stream,
                     x, neigh1, nodes, neigh2, Ws0, Wn0, Ws1, Wn1,
                     Hall, Hmall, WT0s, WT0n, WT1s, WT1n, M1f, out);
  hipLaunchKernelGGL(phaseB_kernel, dim3(7744), dim3(256), 0, stream,
                     x, neigh2, Hall, WT0s, Hmall, C0, M1f);
  hipLaunchKernelGGL(phaseC_kernel, dim3(832), dim3(256), 0, stream,
                     Hmall, WT0n, C0, M1f);
  hipLaunchKernelGGL(phaseD_kernel, dim3(1088), dim3(256), 0, stream,
                     M1f, M1, C0, WT1s, out);
  hipLaunchKernelGGL(phaseE_kernel, dim3(64), dim3(256), 0, stream,
                     M1, WT1n, out);
}

// Round 11
// 171.298 us; speedup vs baseline: 1.7900x; 1.7900x over previous
//
#include <hip/hip_runtime.h>
#include <hip/hip_bf16.h>

// GraphSAGE inference, MI355X. R11: R5 structure + XCD-clustered GEMM tile mapping.
//  phase0 : gather_self(Hall) | weights cast | zero(out)
//  phase1 : gemm0-SELF (XCD-clustered rows) || gather_mean10 || mean25(Hall)->H0m
//  phase2 : gemm0-NEIGHBOR (XCD-clustered rows)
//  phase3 : M1 = bf16(mean25(C1all rows<25600))
//  gemm1  : out = C0@Ws1 + M1@Wn1 (split-K, f32 atomics)
// XCD clustering: 4 col-tiles sharing an A row-tile map to the same XCD
// (wg->XCD is round-robin in dispatch order) -> A-tile HBM-fetched once, L2-reused.

#define DEVINL __device__ __forceinline__

typedef __bf16 bf16x8 __attribute__((ext_vector_type(8)));
typedef float f32x4 __attribute__((ext_vector_type(4)));

DEVINL unsigned short f2bf(float f) {
  union { float f; unsigned u; } v; v.f = f;
  unsigned r = v.u + 0x7FFFu + ((v.u >> 16) & 1u);  // RNE
  return (unsigned short)(r >> 16);
}
DEVINL float bf2f(unsigned short h) {
  union { unsigned u; float f; } v; v.u = ((unsigned)h) << 16;
  return v.f;
}

DEVINL void gload_lds16(const void* g, void* l) {
  __builtin_amdgcn_global_load_lds(
      (const __attribute__((address_space(1))) void*)g,
      (__attribute__((address_space(3))) void*)l, 16, 0, 0);
}

// ---- NT GEMM core: 128x128 tile, BK in {32,64}, 4 waves 2x2, 16x16x32 bf16 MFMA.
// EPI 0: relu + bf16 store to C1[row][col0+...] (ld 1024). EPI 1: f32 atomicAdd out.
template <int EPI, int BK>
DEVINL void gemm_core(const unsigned short* __restrict__ A, int lda,
                      const unsigned short* __restrict__ Bt, int ldb,
                      int Kc, long tm, long tn, int col0,
                      unsigned short* __restrict__ C1, float* __restrict__ out, int ldc,
                      unsigned short* As, unsigned short* Bs) {
  const int t = threadIdx.x;
  const int w = t >> 6;
  const int l = t & 63;
  const int wm = w >> 1, wn = w & 1;
  f32x4 acc[4][4] = {};
  constexpr int LPR = BK / 8;            // lanes per row (16B chunks)
  constexpr int RPW = 64 / LPR;          // rows per wave-gload
  constexpr int ROUNDS = 128 / (4 * RPW);
  constexpr int NS = BK / 32;            // k-slices per iter
  const int s_r = l / LPR;
  const int s_kc = (l % LPR) * 8;

  for (int kt = 0; kt < Kc; kt += BK) {
    __syncthreads();  // LDS free
    #pragma unroll
    for (int r = 0; r < ROUNDS; ++r) {
      const int chunk = r * (4 * RPW) + w * RPW;
      gload_lds16(A + (size_t)(tm + chunk + s_r) * lda + kt + s_kc, As + chunk * BK);
      gload_lds16(Bt + (size_t)(tn + chunk + s_r) * ldb + kt + s_kc, Bs + chunk * BK);
    }
    __syncthreads();  // staged (barrier drains vmcnt)

    bf16x8 af[4][NS], bfr[4][NS];
    const unsigned short* Ab = As + ((size_t)(wm * 64 + (l & 15)) * BK + (l >> 4) * 8);
    const unsigned short* Bb = Bs + ((size_t)(wn * 64 + (l & 15)) * BK + (l >> 4) * 8);
    #pragma unroll
    for (int f = 0; f < 4; ++f)
      #pragma unroll
      for (int s = 0; s < NS; ++s) {
        af[f][s] = *reinterpret_cast<const bf16x8*>(Ab + f * 16 * BK + s * 32);
        bfr[f][s] = *reinterpret_cast<const bf16x8*>(Bb + f * 16 * BK + s * 32);
      }
    #pragma unroll
    for (int s = 0; s < NS; ++s)   // K ascending (matches prior rounds' numerics)
      #pragma unroll
      for (int i = 0; i < 4; ++i)
        #pragma unroll
        for (int j = 0; j < 4; ++j)
          acc[i][j] = __builtin_amdgcn_mfma_f32_16x16x32_bf16(af[i][s], bfr[j][s], acc[i][j], 0, 0, 0);
  }

  // epilogue: C/D layout col = l&15, row = (l>>4)*4 + r  [m89/m91 verified]
  const int q = l >> 4, cl = l & 15;
  #pragma unroll
  for (int i = 0; i < 4; ++i)
    #pragma unroll
    for (int j = 0; j < 4; ++j)
      #pragma unroll
      for (int r = 0; r < 4; ++r) {
        const long row = tm + wm * 64 + i * 16 + q * 4 + r;
        const long col = col0 + tn + wn * 64 + j * 16 + cl;
        if (EPI == 0) C1[row * 1024 + col] = f2bf(fmaxf(acc[i][j][r], 0.f));
        else          atomicAdd(out + row * ldc + col, acc[i][j][r]);
      }
}

// XCD-clustered tile map for 832 = 208 rowblocks x 4 colblocks.
// b = xcd + 8*(4*rblk + col) -> row = xcd + 8*rblk, so the 4 col-tiles of a
// row share b%8 (same XCD under round-robin dispatch) and are dispatched
// within 32 blocks of each other (L2-temporal locality).
DEVINL void xcd_tile_map(int b, long& tm, long& tn) {
  const int xcd = b & 7, idx = b >> 3;
  tm = (long)(xcd + 8 * (idx >> 2)) * 128;
  tn = (long)(idx & 3) * 128;
}

// ---- mean10 of x rows -> bf16 Hmall row (2 rows/block, 256 thr)
DEVINL void mean10_row(const float* __restrict__ x, const int* __restrict__ neigh2,
                       unsigned short* __restrict__ Hmall, int row, int tid) {
  int c4 = (tid & 127) << 2;
  float4 acc = {0.f, 0.f, 0.f, 0.f};
  const int* ip = neigh2 + (size_t)row * 10;
  #pragma unroll
  for (int j = 0; j < 10; ++j) {
    const float4 v = *reinterpret_cast<const float4*>(x + (size_t)ip[j] * 512 + c4);
    acc.x += v.x; acc.y += v.y; acc.z += v.z; acc.w += v.w;
  }
  const float s = 0.1f;
  ushort4 o; o.x = f2bf(acc.x * s); o.y = f2bf(acc.y * s);
  o.z = f2bf(acc.z * s); o.w = f2bf(acc.w * s);
  *reinterpret_cast<ushort4*>(Hmall + (size_t)row * 512 + c4) = o;
}

// ---- mean25 of C1all rows g*25.. at 4-col slice c
DEVINL void mean25_c1(const unsigned short* __restrict__ C1all,
                      unsigned short* __restrict__ M1, int g, int c) {
  float a0 = 0, a1 = 0, a2 = 0, a3 = 0;
  for (int j = 0; j < 25; ++j) {
    ushort4 v = *reinterpret_cast<const ushort4*>(C1all + ((size_t)g * 25 + j) * 1024 + c);
    a0 += bf2f(v.x); a1 += bf2f(v.y); a2 += bf2f(v.z); a3 += bf2f(v.w);
  }
  const float s = 1.0f / 25.0f;
  ushort4 o; o.x = f2bf(a0 * s); o.y = f2bf(a1 * s); o.z = f2bf(a2 * s); o.w = f2bf(a3 * s);
  *reinterpret_cast<ushort4*>(M1 + (size_t)g * 1024 + c) = o;
}

// ---- phase0: gather_self (13312) | weights cast (4096) | zero out (256)
__global__ __launch_bounds__(256) void phase0_kernel(
    const float* __restrict__ x, const int* __restrict__ neigh1, const int* __restrict__ nodes,
    const float* __restrict__ Ws0, const float* __restrict__ Wn0,
    const float* __restrict__ Ws1, const float* __restrict__ Wn1,
    unsigned short* __restrict__ Hall,
    unsigned short* __restrict__ WT0s, unsigned short* __restrict__ WT0n,
    unsigned short* __restrict__ WT1s, unsigned short* __restrict__ WT1n,
    float* __restrict__ out) {
  const int b = blockIdx.x;
  const int tid = threadIdx.x;
  if (b < 13312) {  // gather_self: 2 rows/block
    int row = b * 2 + (tid >> 7);
    int src = row < 25600 ? neigh1[row] : nodes[row - 25600];
    int c4 = (tid & 127) << 2;
    const float4 v = *reinterpret_cast<const float4*>(x + (size_t)src * 512 + c4);
    ushort4 o; o.x = f2bf(v.x); o.y = f2bf(v.y); o.z = f2bf(v.z); o.w = f2bf(v.w);
    *reinterpret_cast<ushort4*>(Hall + (size_t)row * 512 + c4) = o;
  } else if (b < 13312 + 4096) {  // weights -> bf16 [N][K]
    int t = (b - 13312) * 256 + tid;
    int region = t >> 18, local = t & 262143;
    const float* W; unsigned short* WT;
    if (region == 0)      { W = Ws0; WT = WT0s; }
    else if (region == 1) { W = Wn0; WT = WT0n; }
    else if (region == 2) { W = Ws1; WT = WT1s; }
    else                  { W = Wn1; WT = WT1n; }
    int k, n, N;
    if (region < 2) { k = local & 511;  n = local >> 9;  N = 512; }
    else            { k = local & 1023; n = local >> 10; N = 256; }
    WT[local] = f2bf(W[(size_t)k * N + n]);
  } else {  // zero out (1 MB)
    int t = (b - 17408) * 256 + tid;
    reinterpret_cast<float4*>(out)[t] = float4{0.f, 0.f, 0.f, 0.f};
  }
}

// ---- phase1: gemm0-self (832, XCD-clustered) | gather_mean10 (12800) | mean25(Hall)->H0m (512)
__global__ __launch_bounds__(256) void phase1_kernel(
    const float* __restrict__ x, const int* __restrict__ neigh2,
    const unsigned short* __restrict__ Hall, const unsigned short* __restrict__ WT0s,
    unsigned short* __restrict__ Hmall, unsigned short* __restrict__ C1all) {
  __shared__ __align__(16) unsigned short As[128 * 32];
  __shared__ __align__(16) unsigned short Bs[128 * 32];
  const int b = blockIdx.x;
  const int tid = threadIdx.x;
  if (b < 832) {  // self half: cols 0-511, all 26624 rows
    long tm, tn;
    xcd_tile_map(b, tm, tn);
    gemm_core<0, 32>(Hall, 512, WT0s, 512, 512, tm, tn, 0, C1all, nullptr, 0, As, Bs);
  } else if (b < 832 + 12800) {  // mean10 rows 0-25599
    mean10_row(x, neigh2, Hmall, (b - 832) * 2 + (tid >> 7), tid);
  } else {  // H0m = mean25 of Hall bf16 rows -> Hmall rows 25600+
    int g = (b - 13632) * 2 + (tid >> 7);
    int c4 = (tid & 127) << 2;
    float a0 = 0, a1 = 0, a2 = 0, a3 = 0;
    for (int j = 0; j < 25; ++j) {
      ushort4 v = *reinterpret_cast<const ushort4*>(Hall + ((size_t)g * 25 + j) * 512 + c4);
      a0 += bf2f(v.x); a1 += bf2f(v.y); a2 += bf2f(v.z); a3 += bf2f(v.w);
    }
    const float s = 1.0f / 25.0f;
    ushort4 o; o.x = f2bf(a0 * s); o.y = f2bf(a1 * s); o.z = f2bf(a2 * s); o.w = f2bf(a3 * s);
    *reinterpret_cast<ushort4*>(Hmall + ((size_t)25600 + g) * 512 + c4) = o;
  }
}

// ---- phase2: gemm0 neighbor half (832, XCD-clustered): cols 512-1023
__global__ __launch_bounds__(256) void phase2_kernel(
    const unsigned short* __restrict__ Hmall, const unsigned short* __restrict__ WT0n,
    unsigned short* __restrict__ C1all) {
  __shared__ __align__(16) unsigned short As[128 * 32];
  __shared__ __align__(16) unsigned short Bs[128 * 32];
  long tm, tn;
  xcd_tile_map(blockIdx.x, tm, tn);
  gemm_core<0, 32>(Hmall, 512, WT0n, 512, 512, tm, tn, 512, C1all, nullptr, 0, As, Bs);
}

// ---- phase3: M1[g] = bf16(mean25(C1all)), 1024 cols. 2 groups/block over 512 blocks x 2.
__global__ __launch_bounds__(256) void phase3_kernel(const unsigned short* __restrict__ C1all,
                                                     unsigned short* __restrict__ M1) {
  int g = blockIdx.x;
  int c4 = threadIdx.x << 2;
  mean25_c1(C1all, M1, g, c4);
}

// ---- gemm1: out = C0@Ws1 + M1@Wn1 (split-K by 256, dual pass via z)
__global__ __launch_bounds__(256) void gemm1_kernel(
    const unsigned short* __restrict__ C0, const unsigned short* __restrict__ WT1s,
    const unsigned short* __restrict__ M1, const unsigned short* __restrict__ WT1n,
    float* __restrict__ out) {
  __shared__ __align__(16) unsigned short As[128 * 64];
  __shared__ __align__(16) unsigned short Bs[128 * 64];
  const int pass = blockIdx.z >> 2;
  const int k0 = (blockIdx.z & 3) * 256;
  gemm_core<1, 64>((pass ? M1 : C0) + k0, 1024, (pass ? WT1n : WT1s) + k0, 1024, 256,
                   (long)blockIdx.y * 128, (long)blockIdx.x * 128, 0,
                   nullptr, out, 256, As, Bs);
}

extern "C" void kernel_launch(void* const* d_in, const int* in_sizes, int n_in,
                              void* d_out, int out_size, void* d_ws, size_t ws_size,
                              hipStream_t stream) {
  const float* x      = (const float*)d_in[0];   // [200000, 512]
  const int*   nodes  = (const int*)d_in[1];     // [1024]
  const int*   neigh1 = (const int*)d_in[2];     // [25600]
  const int*   neigh2 = (const int*)d_in[3];     // [256000]
  const float* Ws0    = (const float*)d_in[4];   // [512, 512]
  const float* Wn0    = (const float*)d_in[5];   // [512, 512]
  const float* Ws1    = (const float*)d_in[6];   // [1024, 256]
  const float* Wn1    = (const float*)d_in[7];   // [1024, 256]
  float* out = (float*)d_out;                    // [1024, 256]

  char* p = (char*)d_ws;
  unsigned short* WT0s  = (unsigned short*)p; p += (size_t)512 * 512 * 2;
  unsigned short* WT0n  = (unsigned short*)p; p += (size_t)512 * 512 * 2;
  unsigned short* WT1s  = (unsigned short*)p; p += (size_t)256 * 1024 * 2;
  unsigned short* WT1n  = (unsigned short*)p; p += (size_t)256 * 1024 * 2;
  unsigned short* Hall  = (unsigned short*)p; p += (size_t)26624 * 512 * 2;
  unsigned short* Hmall = (unsigned short*)p; p += (size_t)26624 * 512 * 2;
  unsigned short* C1all = (unsigned short*)p; p += (size_t)26624 * 1024 * 2;
  unsigned short* M1    = (unsigned short*)p; p += (size_t)1024 * 1024 * 2;

  const unsigned short* C0 = C1all + (size_t)25600 * 1024;   // rows 25600+

  hipLaunchKernelGGL(phase0_kernel, dim3(17664), dim3(256), 0, stream,
                     x, neigh1, nodes, Ws0, Wn0, Ws1, Wn1,
                     Hall, WT0s, WT0n, WT1s, WT1n, out);
  hipLaunchKernelGGL(phase1_kernel, dim3(14144), dim3(256), 0, stream,
                     x, neigh2, Hall, WT0s, Hmall, C1all);
  hipLaunchKernelGGL(phase2_kernel, dim3(832), dim3(256), 0, stream,
                     Hmall, WT0n, C1all);
  hipLaunchKernelGGL(phase3_kernel, dim3(1024), dim3(256), 0, stream, C1all, M1);
  hipLaunchKernelGGL(gemm1_kernel, dim3(2, 8, 8), dim3(256), 0, stream,
                     C0, WT1s, M1, WT1n, out);
}